// Round 3
// baseline (275.843 us; speedup 1.0000x reference)
//
#include <hip/hip_runtime.h>

#define SSIM_H 512
#define SSIM_W 512
#define PLANES 96
#define TILE 64
#define GRID_X (SSIM_W / TILE)
#define GRID_Y (SSIM_H / TILE)
#define TOTAL_BLOCKS (GRID_X * GRID_Y * PLANES)  // 6144
#define N_TOTAL 25165824.0

typedef _Float16 half4v __attribute__((ext_vector_type(4)));
typedef _Float16 half8v __attribute__((ext_vector_type(8)));
typedef float float4v __attribute__((ext_vector_type(4)));

struct __align__(16) d2 { double x, y; };

// Gaussian tap k (0..10), sigma=1.5: exp(-(k-5)^2/4.5) / 3.759233
__device__ __forceinline__ float gwf(int k) {
  const float d = (float)(k - 5);
  return __expf(-d * d / 4.5f) * 0.26601171702936207f;
}

// Both conv passes as mfma_f32_16x16x32_f16 against a banded weight matrix.
// Weight fragment value = w[8q + j - (lane&15)]; serves as stage-1 B
// (B[k][n]=w[k-n]) and stage-2 A (A[i][kk]=w[kk-i]) with identical registers.
//
// Round-3 change: Rounds 1-2 proved hipcc re-sinks a source-level register
// prefetch regardless of sched_barrier (VGPR stayed 68 -> binary unchanged,
// 5 serialized HBM round trips per wave). This version issues all 20
// global_load_dwordx4 per lane as OPAQUE INLINE ASM (cannot be sunk/split),
// with counted s_waitcnt vmcnt(16/12/8/4/0) + sched_barrier(0) (rule #18)
// before each row-group's compute -> one pipelined round trip. Rows are
// clamped+masked so all x-interior blocks (48/64) take this path; x-edge
// blocks keep the guarded C++ path (no compiler VMEM interleaves with the
// counted asm waits).
//
// H planes stored column-major [plane][col 64][row 84(pad)] f16. Stride 84
// halves = 42 dwords == 10 mod 32 -> conflict-free (measured 0 conflicts).
__global__ __launch_bounds__(256, 3)
void ssim_l1_kernel(const float* __restrict__ pred,
                    const float* __restrict__ targ,
                    double* __restrict__ partials) {
  __shared__ _Float16 Hs[5][64][84];  // 53,760 B -> 3 blocks/CU
  __shared__ float red[2][4];

  const int tid = (int)threadIdx.x;
  const int wv = tid >> 6;    // wave: owns col-group wv in BOTH stages
  const int lane = tid & 63;
  const int q = lane >> 4;    // quad
  const int m = lane & 15;

  const int tr0 = (int)blockIdx.y * TILE;
  const int tc0 = (int)blockIdx.x * TILE;
  const size_t pbase = (size_t)blockIdx.z * (SSIM_H * SSIM_W);
  const float* __restrict__ xp = pred + pbase;
  const float* __restrict__ yp = targ + pbase;

  // Per-lane banded weight fragment.
  half8v wf;
#pragma unroll
  for (int j = 0; j < 8; ++j) {
    const int k = 8 * q + j - m;
    const float v = (k >= 0 && k <= 10) ? gwf(k) : 0.0f;
    wf[j] = (_Float16)v;
  }

  const int cw = tc0 + 16 * wv;      // wave's output col-group (global)
  const int cbase = cw - 5 + 8 * q;  // first of 8 raw cols for this lane

  float l1 = 0.0f;

  // Phase-B body for one row-group: L1 + f16 convert + 5 MFMAs + Hs stores.
  auto phaseB = [&](int rg, const float* xfv, const float* yfv) {
    // Exact fp32 L1 on core pixels, counted exactly once:
    // core rows hr in [5,69), core cols k = 8q+j in [5,21).
    const int hr = rg * 16 + m;
    if (hr >= 5 && hr < 69) {
#pragma unroll
      for (int j = 0; j < 8; ++j) {
        const int k = 8 * q + j;
        if (k >= 5 && k < 21) l1 += fabsf(xfv[j] - yfv[j]);
      }
    }
    half8v ax, ay, axx, ayy, axy;
#pragma unroll
    for (int j = 0; j < 8; ++j) {
      const float x = xfv[j], y = yfv[j];
      ax[j]  = (_Float16)x;
      ay[j]  = (_Float16)y;
      axx[j] = (_Float16)(x * x);
      ayy[j] = (_Float16)(y * y);
      axy[j] = (_Float16)(x * y);
    }
    const float4v z = {0.0f, 0.0f, 0.0f, 0.0f};
    float4v c0 = __builtin_amdgcn_mfma_f32_16x16x32_f16(ax,  wf, z, 0, 0, 0);
    float4v c1 = __builtin_amdgcn_mfma_f32_16x16x32_f16(ay,  wf, z, 0, 0, 0);
    float4v c2 = __builtin_amdgcn_mfma_f32_16x16x32_f16(axx, wf, z, 0, 0, 0);
    float4v c3 = __builtin_amdgcn_mfma_f32_16x16x32_f16(ayy, wf, z, 0, 0, 0);
    float4v c4 = __builtin_amdgcn_mfma_f32_16x16x32_f16(axy, wf, z, 0, 0, 0);

    // C layout: col=lane&15, row=4q+reg (rows contiguous -> one b64/plane).
    const int hcol = 16 * wv + m;
    const int hrow = rg * 16 + 4 * q;
    half4v h;
    h[0] = (_Float16)c0[0]; h[1] = (_Float16)c0[1];
    h[2] = (_Float16)c0[2]; h[3] = (_Float16)c0[3];
    *(half4v*)&Hs[0][hcol][hrow] = h;
    h[0] = (_Float16)c1[0]; h[1] = (_Float16)c1[1];
    h[2] = (_Float16)c1[2]; h[3] = (_Float16)c1[3];
    *(half4v*)&Hs[1][hcol][hrow] = h;
    h[0] = (_Float16)c2[0]; h[1] = (_Float16)c2[1];
    h[2] = (_Float16)c2[2]; h[3] = (_Float16)c2[3];
    *(half4v*)&Hs[2][hcol][hrow] = h;
    h[0] = (_Float16)c3[0]; h[1] = (_Float16)c3[1];
    h[2] = (_Float16)c3[2]; h[3] = (_Float16)c3[3];
    *(half4v*)&Hs[3][hcol][hrow] = h;
    h[0] = (_Float16)c4[0]; h[1] = (_Float16)c4[1];
    h[2] = (_Float16)c4[2]; h[3] = (_Float16)c4[3];
    *(half4v*)&Hs[4][hcol][hrow] = h;
  };

  // x-interior: every lane's 8-col window is in [0,512) (tc0 != 0, 448).
  const bool xint = (tc0 >= 64) && (tc0 <= 384);

  if (xint) {
    // Rows clamped to [0,511]; y-edge blocks zero invalid rows post-wait.
    const bool rowsafe = (tr0 >= 64) && (tr0 <= 384);

    // ---- Issue ALL 20 global_load_dwordx4 (opaque asm: cannot be sunk) ---
    float4v xa0[5], xa1[5], ya0[5], ya1[5];
#pragma unroll
    for (int rg = 0; rg < 5; ++rg) {
      const int grow = tr0 - 5 + rg * 16 + m;
      const int growc = grow < 0 ? 0 : (grow > 511 ? 511 : grow);
      const float* xr = xp + (size_t)growc * SSIM_W + cbase;
      const float* yr = yp + (size_t)growc * SSIM_W + cbase;
      asm volatile("global_load_dwordx4 %0, %1, off"
                   : "=v"(xa0[rg]) : "v"(xr) : "memory");
      asm volatile("global_load_dwordx4 %0, %1, off offset:16"
                   : "=v"(xa1[rg]) : "v"(xr) : "memory");
      asm volatile("global_load_dwordx4 %0, %1, off"
                   : "=v"(ya0[rg]) : "v"(yr) : "memory");
      asm volatile("global_load_dwordx4 %0, %1, off offset:16"
                   : "=v"(ya1[rg]) : "v"(yr) : "memory");
    }

    // ---- Pipelined compute: counted waits, 4 loads retire per rg --------
#pragma unroll
    for (int rg = 0; rg < 5; ++rg) {
      if (rg == 0)      asm volatile("s_waitcnt vmcnt(16)" ::: "memory");
      else if (rg == 1) asm volatile("s_waitcnt vmcnt(12)" ::: "memory");
      else if (rg == 2) asm volatile("s_waitcnt vmcnt(8)" ::: "memory");
      else if (rg == 3) asm volatile("s_waitcnt vmcnt(4)" ::: "memory");
      else              asm volatile("s_waitcnt vmcnt(0)" ::: "memory");
      __builtin_amdgcn_sched_barrier(0);  // rule #18: no hoisting past wait

      float xfv[8], yfv[8];
#pragma unroll
      for (int j = 0; j < 4; ++j) {
        xfv[j] = xa0[rg][j]; xfv[4 + j] = xa1[rg][j];
        yfv[j] = ya0[rg][j]; yfv[4 + j] = ya1[rg][j];
      }
      if (!rowsafe) {
        const int grow = tr0 - 5 + rg * 16 + m;
        const bool okr = (unsigned)grow < (unsigned)SSIM_H;
#pragma unroll
        for (int j = 0; j < 8; ++j) {
          xfv[j] = okr ? xfv[j] : 0.0f;
          yfv[j] = okr ? yfv[j] : 0.0f;
        }
      }
      phaseB(rg, xfv, yfv);
    }
  } else {
    // ---- x-edge blocks (tc0 == 0 or 448): guarded C++ path --------------
    const bool cfast = (cbase >= 0) && (cbase + 7 < SSIM_W);
#pragma unroll
    for (int rg = 0; rg < 5; ++rg) {
      const int grow = tr0 - 5 + rg * 16 + m;
      float xfv[8], yfv[8];
      if ((unsigned)grow < (unsigned)SSIM_H) {
        const float* __restrict__ xr = xp + (size_t)grow * SSIM_W;
        const float* __restrict__ yr = yp + (size_t)grow * SSIM_W;
        if (cfast) {
          float4 a0, a1, b0, b1;
          __builtin_memcpy(&a0, xr + cbase, 16);
          __builtin_memcpy(&a1, xr + cbase + 4, 16);
          __builtin_memcpy(&b0, yr + cbase, 16);
          __builtin_memcpy(&b1, yr + cbase + 4, 16);
          xfv[0] = a0.x; xfv[1] = a0.y; xfv[2] = a0.z; xfv[3] = a0.w;
          xfv[4] = a1.x; xfv[5] = a1.y; xfv[6] = a1.z; xfv[7] = a1.w;
          yfv[0] = b0.x; yfv[1] = b0.y; yfv[2] = b0.z; yfv[3] = b0.w;
          yfv[4] = b1.x; yfv[5] = b1.y; yfv[6] = b1.z; yfv[7] = b1.w;
        } else {
#pragma unroll
          for (int j = 0; j < 8; ++j) {
            const int c = cbase + j;
            const bool ok = (unsigned)c < (unsigned)SSIM_W;
            xfv[j] = ok ? xr[c] : 0.0f;
            yfv[j] = ok ? yr[c] : 0.0f;
          }
        }
      } else {
#pragma unroll
        for (int j = 0; j < 8; ++j) { xfv[j] = 0.0f; yfv[j] = 0.0f; }
      }
      phaseB(rg, xfv, yfv);
    }
  }

  // Wave-private LDS dependency: wait for THIS wave's ds_writes only.
  // (Stage 2 reads only the column slab this wave wrote; no cross-wave
  // traffic, so no __syncthreads needed.) sched_barrier per rule #18.
  asm volatile("s_waitcnt lgkmcnt(0)" ::: "memory");
  __builtin_amdgcn_sched_barrier(0);

  // ---------------- Stage 2: vertical conv + SSIM (wave-private) ----------
  float ssim = 0.0f;
  {
    const int hcol = 16 * wv + m;  // B-frag col n = lane&15, own slab
    // Issue all 40 ds_read_b64 before any stage-2 MFMA.
    half8v bfr[4][5];
#pragma unroll
    for (int rb = 0; rb < 4; ++rb) {
      const int hrow = 16 * rb + 8 * q;  // window row base (band = rb)
#pragma unroll
      for (int p = 0; p < 5; ++p) {
        const _Float16* hp = &Hs[p][hcol][hrow];
        half4v lo = *(const half4v*)hp;
        half4v hi = *(const half4v*)(hp + 4);
        bfr[rb][p] = __builtin_shufflevector(lo, hi, 0, 1, 2, 3, 4, 5, 6, 7);
      }
    }
    const float C1v = 1.0e-4f, C2v = 9.0e-4f;
#pragma unroll
    for (int rb = 0; rb < 4; ++rb) {
      const float4v z = {0.0f, 0.0f, 0.0f, 0.0f};
      float4v acc[5];
#pragma unroll
      for (int p = 0; p < 5; ++p)
        acc[p] = __builtin_amdgcn_mfma_f32_16x16x32_f16(wf, bfr[rb][p], z,
                                                        0, 0, 0);
#pragma unroll
      for (int r = 0; r < 4; ++r) {
        const float mu1 = acc[0][r], mu2 = acc[1][r];
        const float exx = acc[2][r], eyy = acc[3][r], exy = acc[4][r];
        const float m11 = mu1 * mu1, m22 = mu2 * mu2, m12 = mu1 * mu2;
        const float num = (2.0f * m12 + C1v) * (2.0f * (exy - m12) + C2v);
        const float den = (m11 + m22 + C1v) *
                          ((exx - m11) + (eyy - m22) + C2v);
        ssim += num / den;
      }
    }
  }

  // ---- Reduction: wave shuffle -> LDS -> block -> private partial slot ----
  float v0 = l1, v1 = ssim;
#pragma unroll
  for (int off = 32; off > 0; off >>= 1) {
    v0 += __shfl_down(v0, off, 64);
    v1 += __shfl_down(v1, off, 64);
  }
  if (lane == 0) { red[0][wv] = v0; red[1][wv] = v1; }
  __syncthreads();
  if (tid == 0) {
    d2 s;
    s.x = (double)red[0][0] + (double)red[0][1] +
          (double)red[0][2] + (double)red[0][3];
    s.y = (double)red[1][0] + (double)red[1][1] +
          (double)red[1][2] + (double)red[1][3];
    const int bid = ((int)blockIdx.z * GRID_Y + (int)blockIdx.y) * GRID_X +
                    (int)blockIdx.x;
    *(d2*)(partials + 2 * bid) = s;
  }
}

__global__ __launch_bounds__(256)
void finalize_kernel(const double* __restrict__ partials,
                     float* __restrict__ out) {
  __shared__ double red[2][4];
  const int tid = (int)threadIdx.x;
  double L = 0.0, S = 0.0;
  for (int i = tid; i < TOTAL_BLOCKS; i += 256) {
    const d2 v = *(const d2*)(partials + 2 * i);
    L += v.x;
    S += v.y;
  }
#pragma unroll
  for (int off = 32; off > 0; off >>= 1) {
    L += __shfl_down(L, off, 64);
    S += __shfl_down(S, off, 64);
  }
  const int lane = tid & 63, wid = tid >> 6;
  if (lane == 0) { red[0][wid] = L; red[1][wid] = S; }
  __syncthreads();
  if (tid == 0) {
    const double Ls = red[0][0] + red[0][1] + red[0][2] + red[0][3];
    const double Ss = red[1][0] + red[1][1] + red[1][2] + red[1][3];
    const double invN = 1.0 / N_TOTAL;
    out[0] = (float)(0.84 * (Ls * invN) + 0.16 * (1.0 - Ss * invN));
  }
}

extern "C" void kernel_launch(void* const* d_in, const int* in_sizes, int n_in,
                              void* d_out, int out_size, void* d_ws, size_t ws_size,
                              hipStream_t stream) {
  const float* pred = (const float*)d_in[0];
  const float* targ = (const float*)d_in[1];
  float* out = (float*)d_out;
  double* partials = (double*)d_ws;  // 6144 * 2 doubles = 96 KB

  dim3 grid(GRID_X, GRID_Y, PLANES);  // (8, 8, 96)
  ssim_l1_kernel<<<grid, 256, 0, stream>>>(pred, targ, partials);
  finalize_kernel<<<1, 256, 0, stream>>>(partials, out);
}

// Round 4
// 252.233 us; speedup vs baseline: 1.0936x; 1.0936x over previous
//
#include <hip/hip_runtime.h>

#define SSIM_H 512
#define SSIM_W 512
#define PLANES 96
#define TILE 64
#define GRID_X (SSIM_W / TILE)
#define GRID_Y (SSIM_H / TILE)
#define TOTAL_BLOCKS (GRID_X * GRID_Y * PLANES)  // 6144
#define N_TOTAL 25165824.0

typedef _Float16 half4v __attribute__((ext_vector_type(4)));
typedef _Float16 half8v __attribute__((ext_vector_type(8)));
typedef float float4v __attribute__((ext_vector_type(4)));

struct __align__(16) d2 { double x, y; };

// Gaussian tap k (0..10), sigma=1.5: exp(-(k-5)^2/4.5) / 3.759233
__device__ __forceinline__ float gwf(int k) {
  const float d = (float)(k - 5);
  return __expf(-d * d / 4.5f) * 0.26601171702936207f;
}

// Both conv passes as mfma_f32_16x16x32_f16 against a banded weight matrix.
// Weight fragment value = w[8q + j - (lane&15)]; serves as stage-1 B
// (B[k][n]=w[k-n]) and stage-2 A (A[i][kk]=w[kk-i]) with identical registers.
//
// Round-4 change (occupancy attack): measured BW = in-flight bytes/latency;
// three rounds proved per-wave load depth is compiler-hostile (RA spills
// prefetch regs to AGPRs and re-serializes). Waves are the other factor:
//  * Merge x^2 and y^2 planes: SSIM only needs conv(x^2+y^2) (sigma sums).
//    5 planes -> 4. Exact (conv linear). -9 MFMA/wave, -25% LDS.
//  * Rows 84 -> 76: reads need rows <=73; the single access pattern beyond
//    75 is (rb=3,q=3) hi-b64 (rows 76-79) whose taps are identically zero
//    -> clamp its address to row 72 (finite, zero-weighted, bit-exact).
//    Stage-1 stores at rg=4,q=3 (rows 76-79) skipped (never read).
//  * LDS 54.3KB -> 38.9KB: 3 -> 4 blocks/CU (12 -> 16 waves/CU).
//
// H planes stored column-major [plane][col 64][row 76] f16. Stride 76
// halves = 38 dwords: same even-bank structure as previous stride 42
// (measured 0 conflicts there).
__global__ __launch_bounds__(256, 4)
void ssim_l1_kernel(const float* __restrict__ pred,
                    const float* __restrict__ targ,
                    double* __restrict__ partials) {
  __shared__ _Float16 Hs[4][64][76];  // 38,912 B -> 4 blocks/CU
  __shared__ float red[2][4];

  const int tid = (int)threadIdx.x;
  const int wv = tid >> 6;    // wave: owns col-group wv in BOTH stages
  const int lane = tid & 63;
  const int q = lane >> 4;    // quad
  const int m = lane & 15;

  const int tr0 = (int)blockIdx.y * TILE;
  const int tc0 = (int)blockIdx.x * TILE;
  const size_t pbase = (size_t)blockIdx.z * (SSIM_H * SSIM_W);
  const float* __restrict__ xp = pred + pbase;
  const float* __restrict__ yp = targ + pbase;

  // Per-lane banded weight fragment.
  half8v wf;
#pragma unroll
  for (int j = 0; j < 8; ++j) {
    const int k = 8 * q + j - m;
    const float v = (k >= 0 && k <= 10) ? gwf(k) : 0.0f;
    wf[j] = (_Float16)v;
  }

  const int cw = tc0 + 16 * wv;      // wave's output col-group (global)
  const int cbase = cw - 5 + 8 * q;  // first of 8 raw cols for this lane
  const bool cfast = (cbase >= 0) && (cbase + 7 < SSIM_W);

  float l1 = 0.0f;

  // ---------------- Stage 1: horizontal conv -> Hs ----------------
#pragma unroll
  for (int rg = 0; rg < 5; ++rg) {
    const int grow = tr0 - 5 + rg * 16 + m;  // raw image row (H row rg*16+m)
    float xf[8], yf[8];
    if ((unsigned)grow < (unsigned)SSIM_H) {
      const float* __restrict__ xr = xp + (size_t)grow * SSIM_W;
      const float* __restrict__ yr = yp + (size_t)grow * SSIM_W;
      if (cfast) {
        float4 a0, a1, b0, b1;
        __builtin_memcpy(&a0, xr + cbase, 16);
        __builtin_memcpy(&a1, xr + cbase + 4, 16);
        __builtin_memcpy(&b0, yr + cbase, 16);
        __builtin_memcpy(&b1, yr + cbase + 4, 16);
        xf[0] = a0.x; xf[1] = a0.y; xf[2] = a0.z; xf[3] = a0.w;
        xf[4] = a1.x; xf[5] = a1.y; xf[6] = a1.z; xf[7] = a1.w;
        yf[0] = b0.x; yf[1] = b0.y; yf[2] = b0.z; yf[3] = b0.w;
        yf[4] = b1.x; yf[5] = b1.y; yf[6] = b1.z; yf[7] = b1.w;
      } else {
#pragma unroll
        for (int j = 0; j < 8; ++j) {
          const int c = cbase + j;
          const bool ok = (unsigned)c < (unsigned)SSIM_W;
          xf[j] = ok ? xr[c] : 0.0f;
          yf[j] = ok ? yr[c] : 0.0f;
        }
      }
    } else {
#pragma unroll
      for (int j = 0; j < 8; ++j) { xf[j] = 0.0f; yf[j] = 0.0f; }
    }

    // Exact fp32 L1 on core pixels, counted exactly once:
    // core rows hr in [5,69), core cols k = 8q+j in [5,21).
    const int hr = rg * 16 + m;
    if (hr >= 5 && hr < 69) {
#pragma unroll
      for (int j = 0; j < 8; ++j) {
        const int k = 8 * q + j;
        if (k >= 5 && k < 21) l1 += fabsf(xf[j] - yf[j]);
      }
    }

    // Build f16 A-frags for the 4 planes (x, y, x^2+y^2, xy).
    half8v ax, ay, axxyy, axy;
#pragma unroll
    for (int j = 0; j < 8; ++j) {
      const float x = xf[j], y = yf[j];
      ax[j]    = (_Float16)x;
      ay[j]    = (_Float16)y;
      axxyy[j] = (_Float16)(x * x + y * y);
      axy[j]   = (_Float16)(x * y);
    }
    const float4v z = {0.0f, 0.0f, 0.0f, 0.0f};
    float4v c0 = __builtin_amdgcn_mfma_f32_16x16x32_f16(ax,    wf, z, 0, 0, 0);
    float4v c1 = __builtin_amdgcn_mfma_f32_16x16x32_f16(ay,    wf, z, 0, 0, 0);
    float4v c2 = __builtin_amdgcn_mfma_f32_16x16x32_f16(axxyy, wf, z, 0, 0, 0);
    float4v c3 = __builtin_amdgcn_mfma_f32_16x16x32_f16(axy,   wf, z, 0, 0, 0);

    // C layout: col=lane&15, row=4q+reg (rows contiguous -> one b64/plane).
    // Skip rg=4,q=3 (rows 76-79): beyond the 76-row array, and never read.
    if (rg != 4 || q != 3) {
      const int hcol = 16 * wv + m;
      const int hrow = rg * 16 + 4 * q;
      half4v h;
      h[0] = (_Float16)c0[0]; h[1] = (_Float16)c0[1];
      h[2] = (_Float16)c0[2]; h[3] = (_Float16)c0[3];
      *(half4v*)&Hs[0][hcol][hrow] = h;
      h[0] = (_Float16)c1[0]; h[1] = (_Float16)c1[1];
      h[2] = (_Float16)c1[2]; h[3] = (_Float16)c1[3];
      *(half4v*)&Hs[1][hcol][hrow] = h;
      h[0] = (_Float16)c2[0]; h[1] = (_Float16)c2[1];
      h[2] = (_Float16)c2[2]; h[3] = (_Float16)c2[3];
      *(half4v*)&Hs[2][hcol][hrow] = h;
      h[0] = (_Float16)c3[0]; h[1] = (_Float16)c3[1];
      h[2] = (_Float16)c3[2]; h[3] = (_Float16)c3[3];
      *(half4v*)&Hs[3][hcol][hrow] = h;
    }
  }

  // Wave-private LDS dependency: wait for THIS wave's ds_writes only.
  // (Stage 2 reads only the column slab this wave wrote; no cross-wave
  // traffic, so no __syncthreads needed.) sched_barrier per rule #18.
  asm volatile("s_waitcnt lgkmcnt(0)" ::: "memory");
  __builtin_amdgcn_sched_barrier(0);

  // ---------------- Stage 2: vertical conv + SSIM (wave-private) ----------
  float ssim = 0.0f;
  {
    const int hcol = 16 * wv + m;  // B-frag col n = lane&15, own slab
    // Issue all 32 ds_read_b64 before any stage-2 MFMA.
    half8v bfr[4][4];
#pragma unroll
    for (int rb = 0; rb < 4; ++rb) {
      const int hrow = 16 * rb + 8 * q;  // window row base (band = rb)
      // hi half would read rows hrow+4..hrow+7; for rb=3,q=3 that is rows
      // 76-79 whose taps w[kk-i] (kk>=28, i<=15) are identically zero ->
      // clamp to row 72 (valid, finite, zero-weighted: bit-exact result).
      const int hrow_hi = (hrow + 4 <= 72) ? hrow + 4 : 72;
#pragma unroll
      for (int p = 0; p < 4; ++p) {
        half4v lo = *(const half4v*)&Hs[p][hcol][hrow];
        half4v hi = *(const half4v*)&Hs[p][hcol][hrow_hi];
        bfr[rb][p] = __builtin_shufflevector(lo, hi, 0, 1, 2, 3, 4, 5, 6, 7);
      }
    }
    const float C1v = 1.0e-4f, C2v = 9.0e-4f;
#pragma unroll
    for (int rb = 0; rb < 4; ++rb) {
      const float4v z = {0.0f, 0.0f, 0.0f, 0.0f};
      float4v acc[4];
#pragma unroll
      for (int p = 0; p < 4; ++p)
        acc[p] = __builtin_amdgcn_mfma_f32_16x16x32_f16(wf, bfr[rb][p], z,
                                                        0, 0, 0);
#pragma unroll
      for (int r = 0; r < 4; ++r) {
        const float mu1 = acc[0][r], mu2 = acc[1][r];
        const float exxyy = acc[2][r], exy = acc[3][r];
        const float m11 = mu1 * mu1, m22 = mu2 * mu2, m12 = mu1 * mu2;
        const float num = (2.0f * m12 + C1v) * (2.0f * (exy - m12) + C2v);
        const float den = (m11 + m22 + C1v) *
                          ((exxyy - m11 - m22) + C2v);
        ssim += num / den;
      }
    }
  }

  // ---- Reduction: wave shuffle -> LDS -> block -> private partial slot ----
  float v0 = l1, v1 = ssim;
#pragma unroll
  for (int off = 32; off > 0; off >>= 1) {
    v0 += __shfl_down(v0, off, 64);
    v1 += __shfl_down(v1, off, 64);
  }
  if (lane == 0) { red[0][wv] = v0; red[1][wv] = v1; }
  __syncthreads();
  if (tid == 0) {
    d2 s;
    s.x = (double)red[0][0] + (double)red[0][1] +
          (double)red[0][2] + (double)red[0][3];
    s.y = (double)red[1][0] + (double)red[1][1] +
          (double)red[1][2] + (double)red[1][3];
    const int bid = ((int)blockIdx.z * GRID_Y + (int)blockIdx.y) * GRID_X +
                    (int)blockIdx.x;
    *(d2*)(partials + 2 * bid) = s;
  }
}

__global__ __launch_bounds__(256)
void finalize_kernel(const double* __restrict__ partials,
                     float* __restrict__ out) {
  __shared__ double red[2][4];
  const int tid = (int)threadIdx.x;
  double L = 0.0, S = 0.0;
  for (int i = tid; i < TOTAL_BLOCKS; i += 256) {
    const d2 v = *(const d2*)(partials + 2 * i);
    L += v.x;
    S += v.y;
  }
#pragma unroll
  for (int off = 32; off > 0; off >>= 1) {
    L += __shfl_down(L, off, 64);
    S += __shfl_down(S, off, 64);
  }
  const int lane = tid & 63, wid = tid >> 6;
  if (lane == 0) { red[0][wid] = L; red[1][wid] = S; }
  __syncthreads();
  if (tid == 0) {
    const double Ls = red[0][0] + red[0][1] + red[0][2] + red[0][3];
    const double Ss = red[1][0] + red[1][1] + red[1][2] + red[1][3];
    const double invN = 1.0 / N_TOTAL;
    out[0] = (float)(0.84 * (Ls * invN) + 0.16 * (1.0 - Ss * invN));
  }
}

extern "C" void kernel_launch(void* const* d_in, const int* in_sizes, int n_in,
                              void* d_out, int out_size, void* d_ws, size_t ws_size,
                              hipStream_t stream) {
  const float* pred = (const float*)d_in[0];
  const float* targ = (const float*)d_in[1];
  float* out = (float*)d_out;
  double* partials = (double*)d_ws;  // 6144 * 2 doubles = 96 KB

  dim3 grid(GRID_X, GRID_Y, PLANES);  // (8, 8, 96)
  ssim_l1_kernel<<<grid, 256, 0, stream>>>(pred, targ, partials);
  finalize_kernel<<<1, 256, 0, stream>>>(partials, out);
}